// Round 5
// baseline (4847.791 us; speedup 1.0000x reference)
//
#include <hip/hip_runtime.h>
#include <cstdint>
#include <cstddef>

#define T_S 64

typedef __attribute__((ext_vector_type(4))) float f32x4;
typedef __attribute__((ext_vector_type(8))) short bh8;

__device__ __forceinline__ unsigned short f2b(float f) {
  uint32_t x = __builtin_bit_cast(uint32_t, f);
  uint32_t r = (x + 0x7FFFu + ((x >> 16) & 1u)) >> 16;
  return (unsigned short)r;
}
__device__ __forceinline__ float b2f(unsigned short u) {
  uint32_t v = ((uint32_t)u) << 16;
  return __builtin_bit_cast(float, v);
}

// grid barrier: monotone counter, agent scope. Safe because 86KB dynamic LDS
// forces 1 block/CU -> all 256 blocks physically co-resident (no stacking).
__device__ __forceinline__ void gbar(int* bar, int target) {
  __syncthreads();
  if (threadIdx.x == 0) {
    __threadfence();
    __hip_atomic_fetch_add(bar, 1, __ATOMIC_RELEASE, __HIP_MEMORY_SCOPE_AGENT);
    while (__hip_atomic_load(bar, __ATOMIC_ACQUIRE, __HIP_MEMORY_SCOPE_AGENT) < target)
      __builtin_amdgcn_s_sleep(1);
    __threadfence();
  }
  __syncthreads();
}

// ======================= prep =======================

// f32 -> bf16 bulk convert (n4 float4s)
__global__ void k_conv(const float* __restrict__ src, unsigned short* __restrict__ dst, int n4) {
  int i = blockIdx.x * blockDim.x + threadIdx.x;
  int stride = gridDim.x * blockDim.x;
  for (; i < n4; i += stride) {
    float4 v = ((const float4*)src)[i];
    ushort4 o; o.x = f2b(v.x); o.y = f2b(v.y); o.z = f2b(v.z); o.w = f2b(v.w);
    ((ushort4*)dst)[i] = o;
  }
}

// transpose-convert: z=0 Wx -> WxT[4096][1024]; z=1/2 Wh/Wa -> PW[4096][2048]
// PW row order permuted for k_steps' B staging: actual col = q*1024+cj*16+gl
// -> prow = cj*64 + q*16 + gl ; k-half (z-1) selects Wh|Wa.
__global__ __launch_bounds__(256) void k_tw3(
    const float* __restrict__ Wx, const float* __restrict__ Wh,
    const float* __restrict__ Wa,
    unsigned short* __restrict__ WxT, unsigned short* __restrict__ PW) {
  __shared__ float tile[64][65];
  int j0 = blockIdx.x * 64;   // col 0..4095
  int k0 = blockIdx.y * 64;   // k   0..1023
  int z = blockIdx.z;
  const float* src = (z == 0) ? Wx : (z == 1) ? Wh : Wa;
  for (int i = threadIdx.x; i < 4096; i += 256) {
    int r = i >> 6, c = i & 63;     // r: k-offset, c: col-offset (coalesced read)
    tile[r][c] = src[(size_t)(k0 + r) * 4096 + (j0 + c)];
  }
  __syncthreads();
  for (int i = threadIdx.x; i < 4096; i += 256) {
    int r = i >> 6, c = i & 63;     // r: col-offset, c: k-offset (coalesced write)
    int col = j0 + r;
    unsigned short v = f2b(tile[c][r]);
    if (z == 0) {
      WxT[(size_t)col * 1024 + (k0 + c)] = v;
    } else {
      int prow = ((col & 1023) >> 4) * 64 + (col >> 10) * 16 + (col & 15);
      PW[(size_t)prow * 2048 + (size_t)(z - 1) * 1024 + (k0 + c)] = v;
    }
  }
}

// xb2[(t*256+n)][k] = bf16(x[n][t][k])
__global__ __launch_bounds__(256) void k_conv_x2(
    const float* __restrict__ x, unsigned short* __restrict__ xb2) {
  int b = blockIdx.x, tid = threadIdx.x;
  #pragma unroll
  for (int rr = 0; rr < 4; ++rr) {
    int r = b * 4 + rr;
    int t = r >> 8, n = r & 255;
    const float4* src = (const float4*)(x + ((size_t)n * 64 + t) * 1024);
    float4 v = src[tid];
    ushort4 o; o.x = f2b(v.x); o.y = f2b(v.y); o.z = f2b(v.z); o.w = f2b(v.w);
    ((ushort4*)(xb2 + (size_t)r * 1024))[tid] = o;
  }
}

// h0 = c0 = mean(A over 16); h -> hx[n][0..1024) with row stride 2048
__global__ __launch_bounds__(256) void k_init2(
    const float* __restrict__ A, unsigned short* __restrict__ hx,
    float* __restrict__ cst) {
  int idx = blockIdx.x * 256 + threadIdx.x;   // n*1024+h
  const float4* a4 = (const float4*)(A + (size_t)idx * 16);
  float s = 0.f;
  #pragma unroll
  for (int q = 0; q < 4; ++q) { float4 v = a4[q]; s += v.x + v.y + v.z + v.w; }
  s *= 0.0625f;
  cst[idx] = s;
  hx[(size_t)(idx >> 10) * 2048 + (idx & 1023)] = f2b(s);
}

// h0 for Tier-0 layout (row stride 1024)
__global__ __launch_bounds__(256) void k_init1(
    const float* __restrict__ A, unsigned short* __restrict__ hb,
    float* __restrict__ cst) {
  int idx = blockIdx.x * 256 + threadIdx.x;
  const float4* a4 = (const float4*)(A + (size_t)idx * 16);
  float s = 0.f;
  #pragma unroll
  for (int q = 0; q < 4; ++q) { float4 v = a4[q]; s += v.x + v.y + v.z + v.w; }
  s *= 0.0625f;
  cst[idx] = s;
  hb[idx] = f2b(s);
}

// C[M][4096] bf16 = A[M][1024] @ Bt[4096][1024]^T (xproj precompute)
__global__ __launch_bounds__(512) void k_gemm(
    const unsigned short* __restrict__ Asrc,
    const unsigned short* __restrict__ Bt,
    unsigned short* __restrict__ C) {
  __shared__ __align__(16) unsigned short smem[36864];
  int tid = threadIdx.x;
  int bx = blockIdx.x, by = blockIdx.y;
  int lane = tid & 63, wave = tid >> 6;
  int wr = wave >> 1, wc = wave & 1;
  int srow = tid >> 3;
  int scol = (tid & 7) * 8;
  const unsigned short* arow0 = Asrc + ((size_t)(bx * 128 + srow)) * 1024 + scol;
  const unsigned short* arow1 = arow0 + (size_t)64 * 1024;
  const unsigned short* brow0 = Bt + ((size_t)(by * 128 + srow)) * 1024 + scol;
  const unsigned short* brow1 = brow0 + (size_t)64 * 1024;

  f32x4 acc[2][4];
  #pragma unroll
  for (int m = 0; m < 2; ++m)
    #pragma unroll
    for (int nn = 0; nn < 4; ++nn) acc[m][nn] = {0.f, 0.f, 0.f, 0.f};

  uint4 ra0, ra1, rb0, rb1;
  auto gload = [&](int kt) {
    int k0 = kt * 64;
    ra0 = *(const uint4*)(arow0 + k0);
    ra1 = *(const uint4*)(arow1 + k0);
    rb0 = *(const uint4*)(brow0 + k0);
    rb1 = *(const uint4*)(brow1 + k0);
  };
  int frow = lane & 15, fk = (lane >> 4) * 8;
  gload(0);
  int cur = 0;
  for (int kt = 0; kt < 16; ++kt) {
    unsigned short* As = smem + cur * 18432;
    unsigned short* Bs = As + 9216;
    *(uint4*)(As + srow * 72 + scol) = ra0;
    *(uint4*)(As + (srow + 64) * 72 + scol) = ra1;
    *(uint4*)(Bs + srow * 72 + scol) = rb0;
    *(uint4*)(Bs + (srow + 64) * 72 + scol) = rb1;
    __syncthreads();
    if (kt + 1 < 16) gload(kt + 1);
    #pragma unroll
    for (int kk = 0; kk < 2; ++kk) {
      bh8 af[2], bf[4];
      #pragma unroll
      for (int m = 0; m < 2; ++m)
        af[m] = *(const bh8*)(As + (wr * 32 + m * 16 + frow) * 72 + kk * 32 + fk);
      #pragma unroll
      for (int nn = 0; nn < 4; ++nn)
        bf[nn] = *(const bh8*)(Bs + (wc * 64 + nn * 16 + frow) * 72 + kk * 32 + fk);
      #pragma unroll
      for (int m = 0; m < 2; ++m)
        #pragma unroll
        for (int nn = 0; nn < 4; ++nn)
          acc[m][nn] = __builtin_amdgcn_mfma_f32_16x16x32_bf16(af[m], bf[nn], acc[m][nn], 0, 0, 0);
    }
    cur ^= 1;
  }
  int rbase = bx * 128 + wr * 32 + (lane >> 4) * 4;
  int cbase = by * 128 + wc * 64 + frow;
  #pragma unroll
  for (int m = 0; m < 2; ++m)
    #pragma unroll
    for (int nn = 0; nn < 4; ++nn)
      #pragma unroll
      for (int reg = 0; reg < 4; ++reg)
        C[(size_t)(rbase + m * 16 + reg) * 4096 + (cbase + nn * 16)] = f2b(acc[m][nn][reg]);
}

// ======================= persistent step loop =======================
// 256 blocks x 512 thr, 86KB dyn LDS (forces 1 blk/CU -> co-residency).
// Per t: [S+T: n=bid scores/softmax/attn -> hx_cur attn half] BAR
//        [G: (cj,cn) 64n x 16hcols, K=2048 MFMA + LSTM cell -> hx_next] BAR
__global__ __launch_bounds__(512, 1) void k_steps(
    const unsigned short* __restrict__ Ab,     // [256][1024][16]
    const unsigned short* __restrict__ PW,     // [4096][2048] permuted Wh|Wa
    const unsigned short* __restrict__ xproj,  // [(t*256+n)][4096]
    const float* __restrict__ bias,
    unsigned short* __restrict__ hxA,          // [256][2048] = [h|attn]
    unsigned short* __restrict__ hxB,
    float* __restrict__ cst,
    float* __restrict__ out,
    int* __restrict__ bar) {
  extern __shared__ __align__(16) unsigned short smem[];
  const int tid = threadIdx.x;
  const int bid = blockIdx.x;
  const int lane = tid & 63, wave = tid >> 6;
  const int wr = wave >> 1, wc = wave & 1;
  const int frow = lane & 15, fk = (lane >> 4) * 8;
  // XCD-grouped decomposition: the 4 blocks sharing cj land on one XCD
  const int cj = (bid & 7) * 8 + ((bid >> 3) & 7);
  const int cn = bid >> 6;
  const int nbase = cn * 64, j0 = cj * 16;
  const int srow = tid >> 3;          // 0..63
  const int scol = (tid & 7) * 16;    // 0,16,..,112
  const unsigned short* bsrc = PW + ((size_t)(cj * 64 + srow)) * 2048 + scol;
  const int nA = bid;                 // S+T batch index

  int nb = 0;
  for (int t = 0; t < 64; ++t) {
    unsigned short* hxc = (t & 1) ? hxB : hxA;
    unsigned short* hxn = (t & 1) ? hxA : hxB;

    // ---------- Phase S+T: attention for n = bid ----------
    {
      uint hh = *(const uint*)(hxc + (size_t)nA * 2048 + tid * 2);
      float hv0 = b2f((unsigned short)(hh & 0xffff));
      float hv1 = b2f((unsigned short)(hh >> 16));
      const unsigned short* ap = Ab + (size_t)nA * 16384 + tid * 32;
      bh8 a0 = *(const bh8*)(ap);        // h=2*tid,   p 0..7
      bh8 a1 = *(const bh8*)(ap + 8);    // h=2*tid,   p 8..15
      bh8 a2 = *(const bh8*)(ap + 16);   // h=2*tid+1, p 0..7
      bh8 a3 = *(const bh8*)(ap + 24);   // h=2*tid+1, p 8..15
      float s[16];
      #pragma unroll
      for (int p = 0; p < 8; ++p) {
        s[p]     = hv0 * b2f((unsigned short)a0[p]) + hv1 * b2f((unsigned short)a2[p]);
        s[8 + p] = hv0 * b2f((unsigned short)a1[p]) + hv1 * b2f((unsigned short)a3[p]);
      }
      #pragma unroll
      for (int p = 0; p < 16; ++p) {
        float v = s[p];
        #pragma unroll
        for (int off = 32; off > 0; off >>= 1) v += __shfl_xor(v, off);
        s[p] = v;
      }
      float* red = (float*)smem;     // [8][16]
      float* scs = red + 128;        // [16]
      if (lane == 0) {
        #pragma unroll
        for (int p = 0; p < 16; ++p) red[wave * 16 + p] = s[p];
      }
      __syncthreads();
      if (tid < 16) {
        float v = 0.f;
        #pragma unroll
        for (int wv = 0; wv < 8; ++wv) v += red[wv * 16 + tid];
        scs[tid] = v * 0.03125f;     // scale = 1/sqrt(1024)
      }
      __syncthreads();
      float sc[16];
      #pragma unroll
      for (int p = 0; p < 16; ++p) sc[p] = scs[p];
      __syncthreads();               // protect smem before GEMM phase reuses it
      float m = sc[0];
      #pragma unroll
      for (int p = 1; p < 16; ++p) m = fmaxf(m, sc[p]);
      float w[16]; float sum = 0.f;
      #pragma unroll
      for (int p = 0; p < 16; ++p) { w[p] = __expf(sc[p] - m); sum += w[p]; }
      float inv = 1.0f / sum;
      float at0 = 0.f, at1 = 0.f;
      #pragma unroll
      for (int p = 0; p < 8; ++p) {
        at0 += w[p] * b2f((unsigned short)a0[p]) + w[8 + p] * b2f((unsigned short)a1[p]);
        at1 += w[p] * b2f((unsigned short)a2[p]) + w[8 + p] * b2f((unsigned short)a3[p]);
      }
      at0 *= inv; at1 *= inv;
      uint packed = (uint)f2b(at0) | ((uint)f2b(at1) << 16);
      *(uint*)(hxc + (size_t)nA * 2048 + 1024 + tid * 2) = packed;
    }
    nb += 1; gbar(bar, nb * 256);

    // ---------- Phase G: gates GEMM K=2048 + cell ----------
    {
      const unsigned short* asrc = hxc + (size_t)(nbase + srow) * 2048 + scol;
      f32x4 acc0 = {0.f, 0.f, 0.f, 0.f};
      f32x4 acc1 = {0.f, 0.f, 0.f, 0.f};
      uint4 ra0, ra1, rb0, rb1;
      auto gload = [&](int kt) {
        const unsigned short* a = asrc + kt * 128;
        const unsigned short* b = bsrc + kt * 128;
        ra0 = *(const uint4*)(a);
        ra1 = *(const uint4*)(a + 8);
        rb0 = *(const uint4*)(b);
        rb1 = *(const uint4*)(b + 8);
      };
      gload(0);
      int cur = 0;
      for (int kt = 0; kt < 16; ++kt) {
        unsigned short* As = smem + cur * 17408;   // 64 x 136 shorts
        unsigned short* Bs = As + 8704;
        *(uint4*)(As + srow * 136 + scol) = ra0;
        *(uint4*)(As + srow * 136 + scol + 8) = ra1;
        *(uint4*)(Bs + srow * 136 + scol) = rb0;
        *(uint4*)(Bs + srow * 136 + scol + 8) = rb1;
        __syncthreads();
        if (kt + 1 < 16) gload(kt + 1);
        #pragma unroll
        for (int kk = 0; kk < 4; ++kk) {
          bh8 af = *(const bh8*)(As + (wr * 16 + frow) * 136 + kk * 32 + fk);
          bh8 b0 = *(const bh8*)(Bs + (wc * 32 + frow) * 136 + kk * 32 + fk);
          bh8 b1 = *(const bh8*)(Bs + (wc * 32 + 16 + frow) * 136 + kk * 32 + fk);
          acc0 = __builtin_amdgcn_mfma_f32_16x16x32_bf16(af, b0, acc0, 0, 0, 0);
          acc1 = __builtin_amdgcn_mfma_f32_16x16x32_bf16(af, b1, acc1, 0, 0, 0);
        }
        cur ^= 1;
      }
      __syncthreads();
      float* a_lds = (float*)smem;   // [64][65]
      {
        int r0 = wr * 16 + (lane >> 4) * 4;
        int c0 = wc * 32 + frow;
        #pragma unroll
        for (int reg = 0; reg < 4; ++reg) {
          a_lds[(r0 + reg) * 65 + c0]      = acc0[reg];
          a_lds[(r0 + reg) * 65 + c0 + 16] = acc1[reg];
        }
      }
      __syncthreads();
      #pragma unroll
      for (int r = 0; r < 2; ++r) {
        int it = r * 512 + tid;
        int row = it >> 4, gl = it & 15;
        int n = nbase + row;
        int g = j0 + gl;
        const unsigned short* xp = xproj + ((size_t)(t * 256 + n)) * 4096 + g;
        float pre[4];
        #pragma unroll
        for (int q = 0; q < 4; ++q)
          pre[q] = a_lds[row * 65 + q * 16 + gl] + b2f(xp[q * 1024]) + bias[q * 1024 + g];
        size_t ci = (size_t)n * 1024 + g;
        float cold = cst[ci];
        float si = 1.0f / (1.0f + __expf(-pre[0]));
        float sf = 1.0f / (1.0f + __expf(-pre[1]));
        float so = 1.0f / (1.0f + __expf(-pre[2]));
        float tg = 2.0f / (1.0f + __expf(-2.0f * pre[3])) - 1.0f;
        float cn2 = sf * cold + si * tg;
        float hn = so * (2.0f / (1.0f + __expf(-2.0f * cn2)) - 1.0f);
        cst[ci] = cn2;
        out[((size_t)n * T_S + t) * 1024 + g] = hn;
        hxn[(size_t)n * 2048 + g] = f2b(hn);
      }
    }
    nb += 1; gbar(bar, nb * 256);
  }
}

// ======================= TIER 0 fallback (round-1, known-good) =======================

__global__ __launch_bounds__(256) void k_prep_w(
    const float* __restrict__ Wx, const float* __restrict__ Wh,
    const float* __restrict__ Wa, unsigned short* __restrict__ WT) {
  __shared__ float tile[64][65];
  int j0 = blockIdx.x * 64;
  int k0 = blockIdx.y * 64;
  const float* src; int kk0;
  if (k0 < 1024)      { src = Wx; kk0 = k0; }
  else if (k0 < 2048) { src = Wh; kk0 = k0 - 1024; }
  else                { src = Wa; kk0 = k0 - 2048; }
  for (int i = threadIdx.x; i < 4096; i += 256) {
    int r = i >> 6, c = i & 63;
    tile[r][c] = src[(size_t)(kk0 + r) * 4096 + (j0 + c)];
  }
  __syncthreads();
  for (int i = threadIdx.x; i < 4096; i += 256) {
    int r = i >> 6, c = i & 63;
    WT[(size_t)(j0 + r) * 3072 + (k0 + c)] = f2b(tile[c][r]);
  }
}

__global__ __launch_bounds__(256) void k_attn(
    const float* __restrict__ A, const unsigned short* __restrict__ hb,
    unsigned short* __restrict__ attnb) {
  int n = blockIdx.x;
  int tid = threadIdx.x;
  int lane = tid & 63, wave = tid >> 6;
  float areg[4][16];
  float s[16];
  #pragma unroll
  for (int p = 0; p < 16; ++p) s[p] = 0.f;
  #pragma unroll
  for (int r = 0; r < 4; ++r) {
    int h = r * 256 + tid;
    size_t base = (size_t)n * 1024 + h;
    const float4* a4 = (const float4*)(A + base * 16);
    #pragma unroll
    for (int q = 0; q < 4; ++q) {
      float4 v = a4[q];
      areg[r][q*4+0] = v.x; areg[r][q*4+1] = v.y;
      areg[r][q*4+2] = v.z; areg[r][q*4+3] = v.w;
    }
    float hv = b2f(hb[base]);
    #pragma unroll
    for (int p = 0; p < 16; ++p) s[p] += hv * areg[r][p];
  }
  #pragma unroll
  for (int p = 0; p < 16; ++p) {
    float v = s[p];
    #pragma unroll
    for (int off = 32; off > 0; off >>= 1) v += __shfl_xor(v, off);
    s[p] = v;
  }
  __shared__ float red[4][16];
  __shared__ float sc_sh[16];
  if (lane == 0) {
    #pragma unroll
    for (int p = 0; p < 16; ++p) red[wave][p] = s[p];
  }
  __syncthreads();
  if (tid < 16) {
    sc_sh[tid] = (red[0][tid] + red[1][tid] + red[2][tid] + red[3][tid]) * 0.03125f;
  }
  __syncthreads();
  float sc[16];
  #pragma unroll
  for (int p = 0; p < 16; ++p) sc[p] = sc_sh[p];
  float m = sc[0];
  #pragma unroll
  for (int p = 1; p < 16; ++p) m = fmaxf(m, sc[p]);
  float e[16]; float sum = 0.f;
  #pragma unroll
  for (int p = 0; p < 16; ++p) { e[p] = __expf(sc[p] - m); sum += e[p]; }
  float inv = 1.0f / sum;
  #pragma unroll
  for (int r = 0; r < 4; ++r) {
    float a = 0.f;
    #pragma unroll
    for (int p = 0; p < 16; ++p) a += areg[r][p] * e[p];
    attnb[(size_t)n * 1024 + r * 256 + tid] = f2b(a * inv);
  }
}

__global__ __launch_bounds__(512) void k_step(
    const unsigned short* __restrict__ xb,
    const unsigned short* __restrict__ WT,
    const float* __restrict__ bias,
    const unsigned short* __restrict__ hr,
    const unsigned short* __restrict__ atb,
    unsigned short* __restrict__ hw,
    float* __restrict__ cst,
    float* __restrict__ out,
    int t)
{
  __shared__ __align__(16) unsigned short smem[18432];
  int tid = threadIdx.x;
  int bn = blockIdx.x;
  int bm = blockIdx.y;
  int lane = tid & 63;
  int wave = tid >> 6;
  int wr = wave >> 1;
  int wc = wave & 1;
  int nbase = bm * 64;
  int j0 = bn * 16;
  int srow = tid >> 3;
  int scol = (tid & 7) * 8;
  int bj = ((srow >> 4) * 1024) + j0 + (srow & 15);
  const unsigned short* bsrc = WT + (size_t)bj * 3072 + scol;
  f32x4 acc0 = {0.f, 0.f, 0.f, 0.f};
  f32x4 acc1 = {0.f, 0.f, 0.f, 0.f};
  uint4 ra, rb;
  auto gload = [&](int kt) {
    int k0 = kt * 64;
    const unsigned short* src; size_t rs; int kloc;
    if (k0 < 1024)      { src = xb + (size_t)t * 1024; rs = (size_t)T_S * 1024; kloc = k0; }
    else if (k0 < 2048) { src = hr;  rs = 1024; kloc = k0 - 1024; }
    else                { src = atb; rs = 1024; kloc = k0 - 2048; }
    ra = *(const uint4*)(src + (size_t)(nbase + srow) * rs + kloc + scol);
    rb = *(const uint4*)(bsrc + k0);
  };
  int frow = lane & 15;
  int fk = (lane >> 4) * 8;
  gload(0);
  int cur = 0;
  for (int kt = 0; kt < 48; ++kt) {
    unsigned short* As = smem + cur * 4608;
    unsigned short* Bs = smem + 9216 + cur * 4608;
    *(uint4*)(As + srow * 72 + scol) = ra;
    *(uint4*)(Bs + srow * 72 + scol) = rb;
    __syncthreads();
    if (kt + 1 < 48) gload(kt + 1);
    #pragma unroll
    for (int kk = 0; kk < 2; ++kk) {
      bh8 af  = *(const bh8*)(As + (wr * 16 + frow) * 72 + kk * 32 + fk);
      bh8 bf0 = *(const bh8*)(Bs + (wc * 32 + frow) * 72 + kk * 32 + fk);
      bh8 bf1 = *(const bh8*)(Bs + (wc * 32 + 16 + frow) * 72 + kk * 32 + fk);
      acc0 = __builtin_amdgcn_mfma_f32_16x16x32_bf16(af, bf0, acc0, 0, 0, 0);
      acc1 = __builtin_amdgcn_mfma_f32_16x16x32_bf16(af, bf1, acc1, 0, 0, 0);
    }
    cur ^= 1;
  }
  __syncthreads();
  float* a_lds = (float*)smem;
  {
    int r0 = wr * 16 + (lane >> 4) * 4;
    int c0 = wc * 32 + frow;
    #pragma unroll
    for (int reg = 0; reg < 4; ++reg) {
      a_lds[(r0 + reg) * 65 + c0]      = acc0[reg];
      a_lds[(r0 + reg) * 65 + c0 + 16] = acc1[reg];
    }
  }
  __syncthreads();
  #pragma unroll
  for (int r = 0; r < 2; ++r) {
    int pi = r * 512 + tid;
    int row = pi >> 4, gl = pi & 15;
    int n = nbase + row;
    int g = j0 + gl;
    float ii = a_lds[row * 65 + gl]      + bias[g];
    float ff = a_lds[row * 65 + 16 + gl] + bias[1024 + g];
    float oo = a_lds[row * 65 + 32 + gl] + bias[2048 + g];
    float gg = a_lds[row * 65 + 48 + gl] + bias[3072 + g];
    size_t ci = (size_t)n * 1024 + g;
    float cold = cst[ci];
    float si = 1.0f / (1.0f + __expf(-ii));
    float sf = 1.0f / (1.0f + __expf(-ff));
    float so = 1.0f / (1.0f + __expf(-oo));
    float tg = 2.0f / (1.0f + __expf(-2.0f * gg)) - 1.0f;
    float cn = sf * cold + si * tg;
    float hn = so * (2.0f / (1.0f + __expf(-2.0f * cn)) - 1.0f);
    cst[ci] = cn;
    out[((size_t)n * T_S + t) * 1024 + g] = hn;
    hw[ci] = f2b(hn);
  }
}

// ======================= host =======================

extern "C" void kernel_launch(void* const* d_in, const int* in_sizes, int n_in,
                              void* d_out, int out_size, void* d_ws, size_t ws_size,
                              hipStream_t stream) {
  const float* x  = (const float*)d_in[0];
  const float* A  = (const float*)d_in[1];
  const float* Wx = (const float*)d_in[2];
  const float* Wh = (const float*)d_in[3];
  const float* Wa = (const float*)d_in[4];
  const float* b  = (const float*)d_in[5];
  float* out = (float*)d_out;
  char* ws = (char*)d_ws;

  if (ws_size >= 204472576ull) {
    // ---- Tier 3: persistent step loop ----
    unsigned short* WxT   = (unsigned short*)(ws);              //   8,388,608
    unsigned short* PW    = (unsigned short*)(ws + 8388608);    //  16,777,216
    unsigned short* xb2   = (unsigned short*)(ws + 25165824);   //  33,554,432
    unsigned short* Ab    = (unsigned short*)(ws + 58720256);   //   8,388,608
    unsigned short* xproj = (unsigned short*)(ws + 67108864);   // 134,217,728
    unsigned short* hxA   = (unsigned short*)(ws + 201326592);  //   1,048,576
    unsigned short* hxB   = (unsigned short*)(ws + 202375168);  //   1,048,576
    float* cst            = (float*)(ws + 203423744);           //   1,048,576
    int* bar              = (int*)(ws + 204472320);             //         256

    hipFuncSetAttribute((const void*)k_steps,
                        hipFuncAttributeMaxDynamicSharedMemorySize, 86016);

    k_tw3<<<dim3(64, 16, 3), 256, 0, stream>>>(Wx, Wh, Wa, WxT, PW);
    k_conv_x2<<<4096, 256, 0, stream>>>(x, xb2);
    k_conv<<<1024, 256, 0, stream>>>(A, Ab, 1048576);
    k_init2<<<1024, 256, 0, stream>>>(A, hxA, cst);
    k_gemm<<<dim3(128, 32), 512, 0, stream>>>(xb2, WxT, xproj);
    hipMemsetAsync(bar, 0, 256, stream);
    k_steps<<<256, 512, 86016, stream>>>(Ab, PW, xproj, b, hxA, hxB, cst, out, bar);
  } else if (ws_size >= 61341696ull) {
    // ---- Tier 0 fallback ----
    unsigned short* WT  = (unsigned short*)(ws);
    unsigned short* xb  = (unsigned short*)(ws + 25165824);
    unsigned short* hA  = (unsigned short*)(ws + 58720256);
    unsigned short* hB  = (unsigned short*)(ws + 59244544);
    unsigned short* atb = (unsigned short*)(ws + 59768832);
    float* cst          = (float*)(ws + 60293120);

    k_prep_w<<<dim3(64, 48), 256, 0, stream>>>(Wx, Wh, Wa, WT);
    k_conv<<<2048, 256, 0, stream>>>(x, xb, 4194304);
    k_init1<<<1024, 256, 0, stream>>>(A, hA, cst);
    for (int t = 0; t < 64; ++t) {
      const unsigned short* hr = (t & 1) ? hB : hA;
      unsigned short* hwv      = (t & 1) ? hA : hB;
      k_attn<<<256, 256, 0, stream>>>(A, hr, atb);
      k_step<<<dim3(64, 4), 512, 0, stream>>>(xb, WT, b, hr, atb, hwv, cst, out, t);
    }
  }
}